// Round 1
// baseline (367.392 us; speedup 1.0000x reference)
//
#include <hip/hip_runtime.h>
#include <math.h>

// Problem constants (from reference setup_inputs)
#define L_SEQ 1024
#define BATCH 64
#define HDIM  1024
#define WPB   4      // waves per block (256 threads)

// ---------------------------------------------------------------------------
// Kernel 1: per-(batch, l-chunk) online-softmax partials (flash-decode style).
// One wave handles one (b, chunk). Lane j owns h = {4j, 256+4j, 512+4j, 768+4j}
// (each float4-strided so a wave's load of 64 lanes x 16B = 1KB contiguous).
// Partial record r = b*split + k:
//   wsC[r*HDIM + h]  = sum_{l in chunk} exp(s_l - m_r) * enc[l,b,h]
//   wsML[2r], wsML[2r+1] = (m_r, lsum_r)
// ---------------------------------------------------------------------------
__global__ __launch_bounds__(256) void attn_partial_kernel(
    const float* __restrict__ enc, const float* __restrict__ dec,
    float* __restrict__ wsC, float* __restrict__ wsML,
    int split, int chunk)
{
    const int tid  = threadIdx.x;
    const int lane = tid & 63;
    const int wave = tid >> 6;
    const int w    = blockIdx.x * WPB + wave;   // global wave id
    const int b    = w / split;
    const int k    = w - b * split;
    const int l0   = k * chunk;

    // Load this lane's slice of dec[b,:] once (16 floats = 4 float4)
    const float4* decv = (const float4*)(dec + (size_t)b * HDIM);
    const float4 d0 = decv[lane];
    const float4 d1 = decv[lane + 64];
    const float4 d2 = decv[lane + 128];
    const float4 d3 = decv[lane + 192];

    float m = -INFINITY;
    float lsum = 0.0f;
    float4 a0 = make_float4(0.f, 0.f, 0.f, 0.f);
    float4 a1 = a0, a2 = a0, a3 = a0;

    for (int l = l0; l < l0 + chunk; ++l) {
        const float4* row = (const float4*)(enc + ((size_t)l * BATCH + b) * HDIM);
        const float4 e0 = row[lane];
        const float4 e1 = row[lane + 64];
        const float4 e2 = row[lane + 128];
        const float4 e3 = row[lane + 192];

        // per-lane partial dot (16 elements)
        float p = e0.x * d0.x + e0.y * d0.y + e0.z * d0.z + e0.w * d0.w;
        p += e1.x * d1.x + e1.y * d1.y + e1.z * d1.z + e1.w * d1.w;
        p += e2.x * d2.x + e2.y * d2.y + e2.z * d2.z + e2.w * d2.w;
        p += e3.x * d3.x + e3.y * d3.y + e3.z * d3.z + e3.w * d3.w;

        // wave64 butterfly reduce -> every lane holds the full dot s
        #pragma unroll
        for (int off = 32; off > 0; off >>= 1)
            p += __shfl_xor(p, off, 64);

        // online softmax update
        const float mn    = fmaxf(m, p);
        const float scale = __expf(m - mn);   // exp(-inf - x) = 0 on first iter
        const float pe    = __expf(p - mn);
        m = mn;
        lsum = lsum * scale + pe;
        a0.x = a0.x * scale + pe * e0.x;  a0.y = a0.y * scale + pe * e0.y;
        a0.z = a0.z * scale + pe * e0.z;  a0.w = a0.w * scale + pe * e0.w;
        a1.x = a1.x * scale + pe * e1.x;  a1.y = a1.y * scale + pe * e1.y;
        a1.z = a1.z * scale + pe * e1.z;  a1.w = a1.w * scale + pe * e1.w;
        a2.x = a2.x * scale + pe * e2.x;  a2.y = a2.y * scale + pe * e2.y;
        a2.z = a2.z * scale + pe * e2.z;  a2.w = a2.w * scale + pe * e2.w;
        a3.x = a3.x * scale + pe * e3.x;  a3.y = a3.y * scale + pe * e3.y;
        a3.z = a3.z * scale + pe * e3.z;  a3.w = a3.w * scale + pe * e3.w;
    }

    // write partial record
    const size_t r = (size_t)b * split + k;
    float4* C = (float4*)(wsC + r * (size_t)HDIM);
    C[lane]       = a0;
    C[lane + 64]  = a1;
    C[lane + 128] = a2;
    C[lane + 192] = a3;
    if (lane == 0) {
        wsML[2 * r]     = m;
        wsML[2 * r + 1] = lsum;
    }
}

// ---------------------------------------------------------------------------
// Kernel 2: combine split partials per batch, write context[b,h].
// One block per b; thread t owns float4 at h = 4t (256*4 = 1024 = HDIM).
// ---------------------------------------------------------------------------
__global__ __launch_bounds__(256) void attn_reduce_kernel(
    const float* __restrict__ wsC, const float* __restrict__ wsML,
    float* __restrict__ out, int split)
{
    const int b = blockIdx.x;
    const int t = threadIdx.x;

    float M = -INFINITY;
    for (int k = 0; k < split; ++k)
        M = fmaxf(M, wsML[2 * ((size_t)b * split + k)]);

    float Ltot = 0.0f;
    float4 acc = make_float4(0.f, 0.f, 0.f, 0.f);
    for (int k = 0; k < split; ++k) {
        const size_t r = (size_t)b * split + k;
        const float wgt = __expf(wsML[2 * r] - M);
        Ltot += wsML[2 * r + 1] * wgt;
        const float4 c = ((const float4*)(wsC + r * (size_t)HDIM))[t];
        acc.x += c.x * wgt;  acc.y += c.y * wgt;
        acc.z += c.z * wgt;  acc.w += c.w * wgt;
    }
    const float inv = 1.0f / Ltot;
    float4 o;
    o.x = acc.x * inv;  o.y = acc.y * inv;
    o.z = acc.z * inv;  o.w = acc.w * inv;
    ((float4*)(out + (size_t)b * HDIM))[t] = o;
}

extern "C" void kernel_launch(void* const* d_in, const int* in_sizes, int n_in,
                              void* d_out, int out_size, void* d_ws, size_t ws_size,
                              hipStream_t stream) {
    const float* enc = (const float*)d_in[0];   // [L, B, H] fp32
    const float* dec = (const float*)d_in[1];   // [1, B, H] fp32
    float* out = (float*)d_out;                 // [B, H] fp32

    // Pick largest split whose partials fit in d_ws (ws_size is launch-invariant,
    // so this choice is identical on every call -> graph-capture safe).
    int split = 32;
    while (split > 1) {
        const size_t need = (size_t)BATCH * split * HDIM * sizeof(float)
                          + (size_t)BATCH * split * 2 * sizeof(float);
        if (need <= ws_size) break;
        split >>= 1;
    }
    const int chunk = L_SEQ / split;

    float* wsC  = (float*)d_ws;
    float* wsML = wsC + (size_t)BATCH * split * HDIM;

    const int nblocks = (BATCH * split) / WPB;  // one wave per (b, chunk)
    attn_partial_kernel<<<nblocks, 256, 0, stream>>>(enc, dec, wsC, wsML, split, chunk);
    attn_reduce_kernel<<<BATCH, 256, 0, stream>>>(wsC, wsML, out, split);
}